// Round 1
// baseline (5139.353 us; speedup 1.0000x reference)
//
#include <hip/hip_runtime.h>

#define H_ 96
#define W_ 320
#define CIN_ 64
#define HC_ 256
#define HW_ (H_*W_)

// ================= conv3x3 + BN(eval) + ReLU head =================
// block = 256 threads: 64 pixels (one row segment) x 4 waves.
// Each thread accumulates 64 output channels (16 outer iters x 4 regs).
// mode 0: write 256-ch output. mode 1 (hm): fuse 1x1 conv (w2,b2) + sigmoid -> heat.
__global__ __launch_bounds__(256) void conv_head(
    const float* __restrict__ in, const float* __restrict__ w1, const float* __restrict__ b1,
    const float* __restrict__ g, const float* __restrict__ be,
    const float* __restrict__ m, const float* __restrict__ v,
    float* __restrict__ out256,
    const float* __restrict__ w2, const float* __restrict__ b2, float* __restrict__ heat,
    int mode)
{
    __shared__ float lin[CIN_*3*66];   // 64 c x 3 rows x 66 cols (halo=1)
    __shared__ float hred[4*3*64];     // cross-wave heat reduction (mode 1)
    int bid = blockIdx.x;
    int xt = bid % 5; int t2 = bid / 5; int y = t2 % H_; int b = t2 / H_;
    int x0 = xt * 64;
    int t = threadIdx.x;

    // stage input tile (zero-padded)
    for (int idx = t; idx < CIN_*3*66; idx += 256) {
        int c = idx / 198;
        int r = idx - c*198;
        int kh = r / 66;
        int col = r - kh*66;
        int gy = y + kh - 1;
        int gx = x0 + col - 1;
        float val = 0.f;
        if (gy >= 0 && gy < H_ && gx >= 0 && gx < W_)
            val = in[((b*CIN_ + c)*H_ + gy)*W_ + gx];
        lin[idx] = val;
    }
    __syncthreads();

    int px = t & 63;
    int wv = __builtin_amdgcn_readfirstlane(t >> 6);   // wave-uniform -> SGPR weight addrs
    float h0 = 0.f, h1 = 0.f, h2 = 0.f;

    for (int og = 0; og < 16; ++og) {
        int baseo = og*16 + wv*4;
        float acc0 = 0.f, acc1 = 0.f, acc2 = 0.f, acc3 = 0.f;
        for (int c = 0; c < CIN_; ++c) {
            const float* wp = w1 + baseo*576 + c*9;    // wave-uniform -> s_load
            float wr[36];
            #pragma unroll
            for (int oi = 0; oi < 4; ++oi)
                #pragma unroll
                for (int k = 0; k < 9; ++k)
                    wr[oi*9+k] = wp[oi*576 + k];
            const float* lp = lin + c*198;
            #pragma unroll
            for (int kh = 0; kh < 3; ++kh) {
                float i0 = lp[kh*66 + px];
                float i1 = lp[kh*66 + px + 1];
                float i2 = lp[kh*66 + px + 2];
                acc0 += i0*wr[0*9+kh*3] + i1*wr[0*9+kh*3+1] + i2*wr[0*9+kh*3+2];
                acc1 += i0*wr[1*9+kh*3] + i1*wr[1*9+kh*3+1] + i2*wr[1*9+kh*3+2];
                acc2 += i0*wr[2*9+kh*3] + i1*wr[2*9+kh*3+1] + i2*wr[2*9+kh*3+2];
                acc3 += i0*wr[3*9+kh*3] + i1*wr[3*9+kh*3+1] + i2*wr[3*9+kh*3+2];
            }
        }
        float accs[4] = {acc0, acc1, acc2, acc3};
        #pragma unroll
        for (int oi = 0; oi < 4; ++oi) {
            int o = baseo + oi;
            float inv = g[o] / sqrtf(v[o] + 1e-5f);
            float val = (accs[oi] + b1[o]) * inv + (be[o] - m[o]*inv);
            val = fmaxf(val, 0.f);
            if (mode == 0) {
                out256[((b*HC_ + o)*H_ + y)*W_ + x0 + px] = val;
            } else {
                h0 += w2[o] * val;
                h1 += w2[HC_ + o] * val;
                h2 += w2[2*HC_ + o] * val;
            }
        }
    }

    if (mode == 1) {
        hred[(wv*3+0)*64 + px] = h0;
        hred[(wv*3+1)*64 + px] = h1;
        hred[(wv*3+2)*64 + px] = h2;
        __syncthreads();
        if (t < 192) {
            int ch = t >> 6; int p = t & 63;
            float s = hred[(0*3+ch)*64+p] + hred[(1*3+ch)*64+p]
                    + hred[(2*3+ch)*64+p] + hred[(3*3+ch)*64+p] + b2[ch];
            heat[((b*3 + ch)*H_ + y)*W_ + x0 + p] = 1.f / (1.f + expf(-s));
        }
    }
}

// ================= NMS + per-class top-100 =================
// one block per (b, c). Non-maxima become exactly 0 (sigmoid > 0 always),
// so compact local maxima into LDS, then 100 argmax rounds (tie: lower index).
#define CAP_ 6144
__global__ __launch_bounds__(256) void topk_stage1(
    const float* __restrict__ heat, float* __restrict__ s1_s, int* __restrict__ s1_i)
{
    int b = blockIdx.x / 3, c = blockIdx.x % 3;
    const float* hp = heat + (size_t)(b*3 + c)*HW_;
    __shared__ float cs[CAP_];
    __shared__ int   ci[CAP_];
    __shared__ int   cnt;
    __shared__ float rs[4]; __shared__ int ri[4]; __shared__ int rsl[4];
    if (threadIdx.x == 0) cnt = 0;
    __syncthreads();

    for (int i = threadIdx.x; i < HW_; i += 256) {
        int y = i / W_, x = i - y*W_;
        float s = hp[i];
        float mx = s;
        for (int dy = -1; dy <= 1; ++dy) {
            int yy = y + dy;
            if (yy < 0 || yy >= H_) continue;
            for (int dx = -1; dx <= 1; ++dx) {
                int xx = x + dx;
                if (xx < 0 || xx >= W_) continue;
                mx = fmaxf(mx, hp[yy*W_ + xx]);
            }
        }
        if (mx == s) {
            int slot = atomicAdd(&cnt, 1);
            if (slot < CAP_) { cs[slot] = s; ci[slot] = i; }
        }
    }
    __syncthreads();
    int n = min(cnt, CAP_);

    for (int k = 0; k < 100; ++k) {
        float bs = -1.f; int bi = 0x7fffffff, bsl = -1;
        for (int j = threadIdx.x; j < n; j += 256) {
            float s = cs[j]; int ind = ci[j];
            if (s > bs || (s == bs && ind < bi)) { bs = s; bi = ind; bsl = j; }
        }
        for (int off = 32; off; off >>= 1) {
            float s2 = __shfl_down(bs, off);
            int i2   = __shfl_down(bi, off);
            int sl2  = __shfl_down(bsl, off);
            if (s2 > bs || (s2 == bs && i2 < bi)) { bs = s2; bi = i2; bsl = sl2; }
        }
        int wvi = threadIdx.x >> 6;
        if ((threadIdx.x & 63) == 0) { rs[wvi] = bs; ri[wvi] = bi; rsl[wvi] = bsl; }
        __syncthreads();
        if (threadIdx.x == 0) {
            float fs = rs[0]; int fi = ri[0]; int fsl = rsl[0];
            for (int w = 1; w < 4; ++w)
                if (rs[w] > fs || (rs[w] == fs && ri[w] < fi)) { fs = rs[w]; fi = ri[w]; fsl = rsl[w]; }
            if (fs < 0.f) { fs = 0.f; fi = 0; }
            else cs[fsl] = -1.f;
            s1_s[(b*3 + c)*100 + k] = fs;
            s1_i[(b*3 + c)*100 + k] = fi;
        }
        __syncthreads();
    }
}

// ================= across-class top-100 =================
// one wave per batch; ties -> lower position j in the (c*k) array (matches lax.top_k).
__global__ __launch_bounds__(64) void topk_stage2(
    const float* __restrict__ s1_s, const int* __restrict__ s1_i,
    float* __restrict__ out_scores, int* __restrict__ sel)
{
    int b = blockIdx.x;
    __shared__ float sc[300]; __shared__ int orig[300];
    for (int j = threadIdx.x; j < 300; j += 64) { sc[j] = s1_s[b*300 + j]; orig[j] = s1_i[b*300 + j]; }
    __syncthreads();
    for (int k = 0; k < 100; ++k) {
        float bs = -2.f; int bj = 0x7fffffff;
        for (int j = threadIdx.x; j < 300; j += 64) {
            float s = sc[j];
            if (s > bs || (s == bs && j < bj)) { bs = s; bj = j; }
        }
        for (int off = 32; off; off >>= 1) {
            float s2 = __shfl_down(bs, off);
            int j2   = __shfl_down(bj, off);
            if (s2 > bs || (s2 == bs && j2 < bj)) { bs = s2; bj = j2; }
        }
        if (threadIdx.x == 0) {
            out_scores[b*100 + k] = (bs < 0.f) ? 0.f : bs;
            sel[b*100 + k] = (bj == 0x7fffffff) ? 0 : orig[bj];
            if (bj != 0x7fffffff) sc[bj] = -2.f;
        }
        __syncthreads();
    }
}

// ================= multi-scale gather (up_pois) =================
__global__ __launch_bounds__(384) void gather_pois(
    const float* __restrict__ up8, const float* __restrict__ up16,
    const int* __restrict__ sel, float* __restrict__ pois)
{
    int bk = blockIdx.x;           // 0..399
    int b = bk / 100;
    int ind = sel[bk];
    int pp = min(max(ind, 0), HW_ - 1);
    int t = threadIdx.x;
    float val;
    if (t < 128) val = up8[((size_t)(b*128 + t))*HW_ + pp/2];
    else         val = up16[((size_t)(b*256 + (t-128)))*HW_ + pp/4];
    pois[(size_t)bk*384 + t] = val;
}

// ================= reg3d constant fill =================
// out[b][o][h][w] = sum_c w[o][c] + bias[o]; shape (8,8,64,320) -> 1310720 elems.
__global__ __launch_bounds__(256) void reg3d_fill(
    const float* __restrict__ w, const float* __restrict__ bias, float* __restrict__ out)
{
    __shared__ float s[8];
    int t = threadIdx.x;
    if (t < 8) {
        float a = 0.f;
        for (int c = 0; c < 64; ++c) a += w[t*64 + c];
        s[t] = a + bias[t];
    }
    __syncthreads();
    int i = blockIdx.x*256 + t;            // float4 index, 327680 total
    int o = (i / 5120) & 7;                // (i*4 / 20480) % 8
    float val = s[o];
    float4 vv = make_float4(val, val, val, val);
    ((float4*)out)[i] = vv;
}

extern "C" void kernel_launch(void* const* d_in, const int* in_sizes, int n_in,
                              void* d_out, int out_size, void* d_ws, size_t ws_size,
                              hipStream_t stream)
{
    const float* up16 = (const float*)d_in[0];
    const float* up8  = (const float*)d_in[1];
    const float* up4  = (const float*)d_in[2];
    const float* HM[6]; const float* DEP[6]; const float* DIM[6]; const float* ROT[6];
    for (int i = 0; i < 6; ++i) {
        HM[i]  = (const float*)d_in[3+i];
        DEP[i] = (const float*)d_in[9+i];
        DIM[i] = (const float*)d_in[15+i];
        ROT[i] = (const float*)d_in[21+i];
    }
    const float* hm_w2 = (const float*)d_in[27];
    const float* hm_b2 = (const float*)d_in[28];
    const float* r3_w  = (const float*)d_in[29];
    const float* r3_b  = (const float*)d_in[30];

    float* out = (float*)d_out;
    float* heat   = out;                       // 4*3*96*320   = 368640
    float* dep    = heat + 368640LL;           // 4*256*96*320 = 31457280
    float* dimo   = dep + 31457280LL;
    float* rot    = dimo + 31457280LL;
    float* scores = rot + 31457280LL;          // 400
    float* pois   = scores + 400;              // 153600
    float* reg3   = pois + 153600;             // 1310720

    float* s1s = (float*)d_ws;                 // 1200 floats
    int*   s1i = (int*)(s1s + 1200);           // 1200 ints
    int*   sel = s1i + 1200;                   // 400 ints

    dim3 blk(256), grd(1920);
    conv_head<<<grd, blk, 0, stream>>>(up4, DEP[0], DEP[1], DEP[2], DEP[3], DEP[4], DEP[5],
                                       dep, nullptr, nullptr, nullptr, 0);
    conv_head<<<grd, blk, 0, stream>>>(up4, DIM[0], DIM[1], DIM[2], DIM[3], DIM[4], DIM[5],
                                       dimo, nullptr, nullptr, nullptr, 0);
    conv_head<<<grd, blk, 0, stream>>>(up4, ROT[0], ROT[1], ROT[2], ROT[3], ROT[4], ROT[5],
                                       rot, nullptr, nullptr, nullptr, 0);
    conv_head<<<grd, blk, 0, stream>>>(up4, HM[0], HM[1], HM[2], HM[3], HM[4], HM[5],
                                       nullptr, hm_w2, hm_b2, heat, 1);
    topk_stage1<<<dim3(12), dim3(256), 0, stream>>>(heat, s1s, s1i);
    topk_stage2<<<dim3(4), dim3(64), 0, stream>>>(s1s, s1i, scores, sel);
    gather_pois<<<dim3(400), dim3(384), 0, stream>>>(up8, up16, sel, pois);
    reg3d_fill<<<dim3(1280), dim3(256), 0, stream>>>(r3_w, r3_b, reg3);
}

// Round 2
// 1466.290 us; speedup vs baseline: 3.5050x; 3.5050x over previous
//
#include <hip/hip_runtime.h>
#include <hip/hip_bf16.h>

#define H_ 96
#define W_ 320
#define CIN_ 64
#define HC_ 256
#define HW_ (H_*W_)

typedef __attribute__((ext_vector_type(8))) short bf16x8;
typedef __attribute__((ext_vector_type(4))) float f32x4;

__device__ inline ushort f2bf(float v){ __hip_bfloat16 h = __float2bfloat16(v); return *(ushort*)&h; }
__device__ inline float bf2f(ushort u){ __hip_bfloat16 h; *(ushort*)&h = u; return __bfloat162float(h); }

struct HeadP { const float *b1, *g, *be, *m, *v; };

// ============ prep: up4 fp32 [b][c][y][x] -> bf16 hi/lo [b][y][x][c] ============
__global__ __launch_bounds__(256) void prep_x(const float* __restrict__ up4,
    ushort* __restrict__ Xhi, ushort* __restrict__ Xlo)
{
    int tid = blockIdx.x*256 + threadIdx.x;      // 983040 threads: pixel*8 + cgroup
    int pix = tid >> 3, cg = tid & 7;
    int b = pix / HW_; int rem = pix - b*HW_;
    ushort hi[8] __attribute__((aligned(16)));
    ushort lo[8] __attribute__((aligned(16)));
    #pragma unroll
    for (int i = 0; i < 8; ++i) {
        int c = cg*8 + i;
        float vv = up4[((size_t)(b*CIN_ + c))*HW_ + rem];
        ushort h = f2bf(vv);
        hi[i] = h;
        lo[i] = f2bf(vv - bf2f(h));
    }
    size_t off = (size_t)pix*64 + cg*8;
    *(uint4*)(Xhi + off) = *(uint4*)hi;
    *(uint4*)(Xlo + off) = *(uint4*)lo;
}

// ===== prep: weights [o][c][3][3] fp32 -> bf16 [plane][kk][o][c]; planes 0-2 = dep/dim/rot, 3 = hm_hi, 4 = hm_lo
__global__ __launch_bounds__(256) void prep_w(
    const float* __restrict__ w_dep, const float* __restrict__ w_dim,
    const float* __restrict__ w_rot, const float* __restrict__ w_hm,
    ushort* __restrict__ Wt)
{
    int tid = blockIdx.x*256 + threadIdx.x;      // 5*147456
    if (tid >= 5*147456) return;
    int p = tid / 147456; int r = tid - p*147456;
    int kk = r / 16384; int o = (r >> 6) & 255; int c = r & 63;
    const float* src = (p==0) ? w_dep : (p==1) ? w_dim : (p==2) ? w_rot : w_hm;
    float v = src[(o*64 + c)*9 + kk];
    ushort h = f2bf(v);
    Wt[tid] = (p==4) ? f2bf(v - bf2f(h)) : h;
}

// stage one (3 rows x 66 cols x 64 c) tile into LDS with c-stride 72 (pad => conflict-free b128)
__device__ inline void stage_tile(ushort* lds, const ushort* __restrict__ X,
                                  int b, int y, int x0, int t)
{
    for (int i = t*8; i < 3*66*64; i += 256*8) {
        int row = i / 4224; int rem = i - row*4224;
        int col = rem >> 6; int c = rem & 63;
        int gy = y + row - 1, gx = x0 + col - 1;
        uint4 v = make_uint4(0u,0u,0u,0u);
        if (gy >= 0 && gy < H_ && gx >= 0 && gx < W_)
            v = *(const uint4*)(X + ((size_t)((b*H_ + gy)*W_ + gx))*64 + c);
        *(uint4*)(lds + (row*66 + col)*72 + c) = v;
    }
}

// ============ dep/dim/rot: bf16 MFMA conv3x3 + BN + ReLU ============
__global__ __launch_bounds__(256,2) void conv3_mfma(
    const ushort* __restrict__ Xhi, const ushort* __restrict__ Wt,
    HeadP hd, HeadP hi_, HeadP hr, float* __restrict__ outbase)
{
    __shared__ ushort Xs[3*66*72];
    int bid = blockIdx.x;
    int xt = bid % 5; int t2 = bid / 5; int y = t2 % H_; int b = t2 / H_;
    int x0 = xt*64;
    int t = threadIdx.x;
    int head = blockIdx.y;

    stage_tile(Xs, Xhi, b, y, x0, t);
    __syncthreads();

    int lane = t & 63, wv = t >> 6;
    int ml = lane & 15, quad = lane >> 4;
    int wvo = wv * 64;
    const ushort* Wp = Wt + head*147456;

    f32x4 acc[4][4];
    #pragma unroll
    for (int mt = 0; mt < 4; ++mt)
        #pragma unroll
        for (int nt = 0; nt < 4; ++nt)
            acc[mt][nt] = (f32x4){0.f,0.f,0.f,0.f};

    for (int kk = 0; kk < 9; ++kk) {
        int kh = kk/3, kw = kk - kh*3;
        const ushort* ldsrow = Xs + (kh*66 + kw)*72;
        #pragma unroll
        for (int chunk = 0; chunk < 2; ++chunk) {
            int c0 = chunk*32 + quad*8;
            bf16x8 Af[4], Bf[4];
            #pragma unroll
            for (int mt = 0; mt < 4; ++mt)
                Af[mt] = *(const bf16x8*)(Wp + (kk*256 + wvo + mt*16 + ml)*64 + c0);
            #pragma unroll
            for (int nt = 0; nt < 4; ++nt)
                Bf[nt] = *(const bf16x8*)(ldsrow + (nt*16 + ml)*72 + c0);
            #pragma unroll
            for (int mt = 0; mt < 4; ++mt)
                #pragma unroll
                for (int nt = 0; nt < 4; ++nt)
                    acc[mt][nt] = __builtin_amdgcn_mfma_f32_16x16x32_bf16(
                        Af[mt], Bf[nt], acc[mt][nt], 0, 0, 0);
        }
    }

    HeadP hp = (head==0) ? hd : (head==1) ? hi_ : hr;
    float* out = outbase + (size_t)head*31457280ll;
    #pragma unroll
    for (int mt = 0; mt < 4; ++mt) {
        int ob = wvo + mt*16 + quad*4;
        #pragma unroll
        for (int r = 0; r < 4; ++r) {
            int o = ob + r;
            float inv = hp.g[o] / sqrtf(hp.v[o] + 1e-5f);
            float sh = hp.be[o] - hp.m[o]*inv;
            float bb = hp.b1[o];
            float* orow = out + ((size_t)(b*HC_ + o)*H_ + y)*W_ + x0;
            #pragma unroll
            for (int nt = 0; nt < 4; ++nt) {
                float val = (acc[mt][nt][r] + bb)*inv + sh;
                orow[nt*16 + ml] = fmaxf(val, 0.f);
            }
        }
    }
}

// ============ hm: bf16x3 split-precision MFMA conv + BN + ReLU + 1x1 + sigmoid ============
__global__ __launch_bounds__(256,2) void convhm_mfma(
    const ushort* __restrict__ Xhi, const ushort* __restrict__ Xlo,
    const ushort* __restrict__ Wt, HeadP hp,
    const float* __restrict__ w2, const float* __restrict__ b2,
    float* __restrict__ heat)
{
    __shared__ ushort Xh[3*66*72];
    __shared__ ushort Xl[3*66*72];
    __shared__ float hred[4][3][64];
    int bid = blockIdx.x;
    int xt = bid % 5; int t2 = bid / 5; int y = t2 % H_; int b = t2 / H_;
    int x0 = xt*64;
    int t = threadIdx.x;

    stage_tile(Xh, Xhi, b, y, x0, t);
    stage_tile(Xl, Xlo, b, y, x0, t);
    __syncthreads();

    int lane = t & 63, wv = t >> 6;
    int ml = lane & 15, quad = lane >> 4;
    int wvo = wv * 64;
    const ushort* Wh = Wt + 3*147456;
    const ushort* Wl = Wt + 4*147456;

    f32x4 acc[4][4];
    #pragma unroll
    for (int mt = 0; mt < 4; ++mt)
        #pragma unroll
        for (int nt = 0; nt < 4; ++nt)
            acc[mt][nt] = (f32x4){0.f,0.f,0.f,0.f};

    for (int kk = 0; kk < 9; ++kk) {
        int kh = kk/3, kw = kk - kh*3;
        const ushort* lrh = Xh + (kh*66 + kw)*72;
        const ushort* lrl = Xl + (kh*66 + kw)*72;
        #pragma unroll
        for (int chunk = 0; chunk < 2; ++chunk) {
            int c0 = chunk*32 + quad*8;
            bf16x8 Ah[4], Al[4], Bh[4], Bl[4];
            #pragma unroll
            for (int mt = 0; mt < 4; ++mt) {
                int wo = (kk*256 + wvo + mt*16 + ml)*64 + c0;
                Ah[mt] = *(const bf16x8*)(Wh + wo);
                Al[mt] = *(const bf16x8*)(Wl + wo);
            }
            #pragma unroll
            for (int nt = 0; nt < 4; ++nt) {
                int xo = (nt*16 + ml)*72 + c0;
                Bh[nt] = *(const bf16x8*)(lrh + xo);
                Bl[nt] = *(const bf16x8*)(lrl + xo);
            }
            #pragma unroll
            for (int mt = 0; mt < 4; ++mt)
                #pragma unroll
                for (int nt = 0; nt < 4; ++nt) {
                    f32x4 a = acc[mt][nt];
                    a = __builtin_amdgcn_mfma_f32_16x16x32_bf16(Ah[mt], Bh[nt], a, 0, 0, 0);
                    a = __builtin_amdgcn_mfma_f32_16x16x32_bf16(Al[mt], Bh[nt], a, 0, 0, 0);
                    a = __builtin_amdgcn_mfma_f32_16x16x32_bf16(Ah[mt], Bl[nt], a, 0, 0, 0);
                    acc[mt][nt] = a;
                }
        }
    }

    float h0[4] = {0,0,0,0}, h1[4] = {0,0,0,0}, h2[4] = {0,0,0,0};
    #pragma unroll
    for (int mt = 0; mt < 4; ++mt) {
        int ob = wvo + mt*16 + quad*4;
        #pragma unroll
        for (int r = 0; r < 4; ++r) {
            int o = ob + r;
            float inv = hp.g[o] / sqrtf(hp.v[o] + 1e-5f);
            float sh = hp.be[o] - hp.m[o]*inv;
            float bb = hp.b1[o];
            float w20 = w2[o], w21 = w2[HC_ + o], w22 = w2[2*HC_ + o];
            #pragma unroll
            for (int nt = 0; nt < 4; ++nt) {
                float val = fmaxf((acc[mt][nt][r] + bb)*inv + sh, 0.f);
                h0[nt] += w20*val; h1[nt] += w21*val; h2[nt] += w22*val;
            }
        }
    }
    #pragma unroll
    for (int nt = 0; nt < 4; ++nt) {
        float a0 = h0[nt]; a0 += __shfl_xor(a0, 16); a0 += __shfl_xor(a0, 32);
        float a1 = h1[nt]; a1 += __shfl_xor(a1, 16); a1 += __shfl_xor(a1, 32);
        float a2 = h2[nt]; a2 += __shfl_xor(a2, 16); a2 += __shfl_xor(a2, 32);
        if (quad == 0) {
            hred[wv][0][nt*16 + ml] = a0;
            hred[wv][1][nt*16 + ml] = a1;
            hred[wv][2][nt*16 + ml] = a2;
        }
    }
    __syncthreads();
    if (t < 192) {
        int ch = t >> 6, p = t & 63;
        float s = hred[0][ch][p] + hred[1][ch][p] + hred[2][ch][p] + hred[3][ch][p] + b2[ch];
        heat[((b*3 + ch)*H_ + y)*W_ + x0 + p] = 1.f/(1.f + expf(-s));
    }
}

// ================= fallback fp32 conv (round-1, kept for small-ws safety) =================
__global__ __launch_bounds__(256) void conv_head(
    const float* __restrict__ in, const float* __restrict__ w1, const float* __restrict__ b1,
    const float* __restrict__ g, const float* __restrict__ be,
    const float* __restrict__ m, const float* __restrict__ v,
    float* __restrict__ out256,
    const float* __restrict__ w2, const float* __restrict__ b2, float* __restrict__ heat,
    int mode)
{
    __shared__ float lin[CIN_*3*66];
    __shared__ float hred[4*3*64];
    int bid = blockIdx.x;
    int xt = bid % 5; int t2 = bid / 5; int y = t2 % H_; int b = t2 / H_;
    int x0 = xt * 64;
    int t = threadIdx.x;
    for (int idx = t; idx < CIN_*3*66; idx += 256) {
        int c = idx / 198; int r = idx - c*198;
        int kh = r / 66; int col = r - kh*66;
        int gy = y + kh - 1; int gx = x0 + col - 1;
        float val = 0.f;
        if (gy >= 0 && gy < H_ && gx >= 0 && gx < W_)
            val = in[((b*CIN_ + c)*H_ + gy)*W_ + gx];
        lin[idx] = val;
    }
    __syncthreads();
    int px = t & 63;
    int wv = __builtin_amdgcn_readfirstlane(t >> 6);
    float h0 = 0.f, h1 = 0.f, h2 = 0.f;
    for (int og = 0; og < 16; ++og) {
        int baseo = og*16 + wv*4;
        float acc0 = 0.f, acc1 = 0.f, acc2 = 0.f, acc3 = 0.f;
        for (int c = 0; c < CIN_; ++c) {
            const float* wp = w1 + baseo*576 + c*9;
            float wr[36];
            #pragma unroll
            for (int oi = 0; oi < 4; ++oi)
                #pragma unroll
                for (int k = 0; k < 9; ++k)
                    wr[oi*9+k] = wp[oi*576 + k];
            const float* lp = lin + c*198;
            #pragma unroll
            for (int kh = 0; kh < 3; ++kh) {
                float i0 = lp[kh*66 + px];
                float i1 = lp[kh*66 + px + 1];
                float i2 = lp[kh*66 + px + 2];
                acc0 += i0*wr[0*9+kh*3] + i1*wr[0*9+kh*3+1] + i2*wr[0*9+kh*3+2];
                acc1 += i0*wr[1*9+kh*3] + i1*wr[1*9+kh*3+1] + i2*wr[1*9+kh*3+2];
                acc2 += i0*wr[2*9+kh*3] + i1*wr[2*9+kh*3+1] + i2*wr[2*9+kh*3+2];
                acc3 += i0*wr[3*9+kh*3] + i1*wr[3*9+kh*3+1] + i2*wr[3*9+kh*3+2];
            }
        }
        float accs[4] = {acc0, acc1, acc2, acc3};
        #pragma unroll
        for (int oi = 0; oi < 4; ++oi) {
            int o = baseo + oi;
            float inv = g[o] / sqrtf(v[o] + 1e-5f);
            float val = (accs[oi] + b1[o]) * inv + (be[o] - m[o]*inv);
            val = fmaxf(val, 0.f);
            if (mode == 0) out256[((b*HC_ + o)*H_ + y)*W_ + x0 + px] = val;
            else { h0 += w2[o]*val; h1 += w2[HC_+o]*val; h2 += w2[2*HC_+o]*val; }
        }
    }
    if (mode == 1) {
        hred[(wv*3+0)*64 + px] = h0;
        hred[(wv*3+1)*64 + px] = h1;
        hred[(wv*3+2)*64 + px] = h2;
        __syncthreads();
        if (t < 192) {
            int ch = t >> 6; int p = t & 63;
            float s = hred[(0*3+ch)*64+p] + hred[(1*3+ch)*64+p]
                    + hred[(2*3+ch)*64+p] + hred[(3*3+ch)*64+p] + b2[ch];
            heat[((b*3 + ch)*H_ + y)*W_ + x0 + p] = 1.f / (1.f + expf(-s));
        }
    }
}

// ================= NMS + per-class top-100 =================
#define CAP_ 6144
__global__ __launch_bounds__(256) void topk_stage1(
    const float* __restrict__ heat, float* __restrict__ s1_s, int* __restrict__ s1_i)
{
    int b = blockIdx.x / 3, c = blockIdx.x % 3;
    const float* hp = heat + (size_t)(b*3 + c)*HW_;
    __shared__ float cs[CAP_];
    __shared__ int   ci[CAP_];
    __shared__ int   cnt;
    __shared__ float rs[4]; __shared__ int ri[4]; __shared__ int rsl[4];
    if (threadIdx.x == 0) cnt = 0;
    __syncthreads();
    for (int i = threadIdx.x; i < HW_; i += 256) {
        int y = i / W_, x = i - y*W_;
        float s = hp[i];
        float mx = s;
        for (int dy = -1; dy <= 1; ++dy) {
            int yy = y + dy;
            if (yy < 0 || yy >= H_) continue;
            for (int dx = -1; dx <= 1; ++dx) {
                int xx = x + dx;
                if (xx < 0 || xx >= W_) continue;
                mx = fmaxf(mx, hp[yy*W_ + xx]);
            }
        }
        if (mx == s) {
            int slot = atomicAdd(&cnt, 1);
            if (slot < CAP_) { cs[slot] = s; ci[slot] = i; }
        }
    }
    __syncthreads();
    int n = min(cnt, CAP_);
    for (int k = 0; k < 100; ++k) {
        float bs = -1.f; int bi = 0x7fffffff, bsl = -1;
        for (int j = threadIdx.x; j < n; j += 256) {
            float s = cs[j]; int ind = ci[j];
            if (s > bs || (s == bs && ind < bi)) { bs = s; bi = ind; bsl = j; }
        }
        for (int off = 32; off; off >>= 1) {
            float s2 = __shfl_down(bs, off);
            int i2   = __shfl_down(bi, off);
            int sl2  = __shfl_down(bsl, off);
            if (s2 > bs || (s2 == bs && i2 < bi)) { bs = s2; bi = i2; bsl = sl2; }
        }
        int wvi = threadIdx.x >> 6;
        if ((threadIdx.x & 63) == 0) { rs[wvi] = bs; ri[wvi] = bi; rsl[wvi] = bsl; }
        __syncthreads();
        if (threadIdx.x == 0) {
            float fs = rs[0]; int fi = ri[0]; int fsl = rsl[0];
            for (int w = 1; w < 4; ++w)
                if (rs[w] > fs || (rs[w] == fs && ri[w] < fi)) { fs = rs[w]; fi = ri[w]; fsl = rsl[w]; }
            if (fs < 0.f) { fs = 0.f; fi = 0; }
            else cs[fsl] = -1.f;
            s1_s[(b*3 + c)*100 + k] = fs;
            s1_i[(b*3 + c)*100 + k] = fi;
        }
        __syncthreads();
    }
}

__global__ __launch_bounds__(64) void topk_stage2(
    const float* __restrict__ s1_s, const int* __restrict__ s1_i,
    float* __restrict__ out_scores, int* __restrict__ sel)
{
    int b = blockIdx.x;
    __shared__ float sc[300]; __shared__ int orig[300];
    for (int j = threadIdx.x; j < 300; j += 64) { sc[j] = s1_s[b*300 + j]; orig[j] = s1_i[b*300 + j]; }
    __syncthreads();
    for (int k = 0; k < 100; ++k) {
        float bs = -2.f; int bj = 0x7fffffff;
        for (int j = threadIdx.x; j < 300; j += 64) {
            float s = sc[j];
            if (s > bs || (s == bs && j < bj)) { bs = s; bj = j; }
        }
        for (int off = 32; off; off >>= 1) {
            float s2 = __shfl_down(bs, off);
            int j2   = __shfl_down(bj, off);
            if (s2 > bs || (s2 == bs && j2 < bj)) { bs = s2; bj = j2; }
        }
        if (threadIdx.x == 0) {
            out_scores[b*100 + k] = (bs < 0.f) ? 0.f : bs;
            sel[b*100 + k] = (bj == 0x7fffffff) ? 0 : orig[bj];
            if (bj != 0x7fffffff) sc[bj] = -2.f;
        }
        __syncthreads();
    }
}

__global__ __launch_bounds__(384) void gather_pois(
    const float* __restrict__ up8, const float* __restrict__ up16,
    const int* __restrict__ sel, float* __restrict__ pois)
{
    int bk = blockIdx.x;
    int b = bk / 100;
    int ind = sel[bk];
    int pp = min(max(ind, 0), HW_ - 1);
    int t = threadIdx.x;
    float val;
    if (t < 128) val = up8[((size_t)(b*128 + t))*HW_ + pp/2];
    else         val = up16[((size_t)(b*256 + (t-128)))*HW_ + pp/4];
    pois[(size_t)bk*384 + t] = val;
}

__global__ __launch_bounds__(256) void reg3d_fill(
    const float* __restrict__ w, const float* __restrict__ bias, float* __restrict__ out)
{
    __shared__ float s[8];
    int t = threadIdx.x;
    if (t < 8) {
        float a = 0.f;
        for (int c = 0; c < 64; ++c) a += w[t*64 + c];
        s[t] = a + bias[t];
    }
    __syncthreads();
    int i = blockIdx.x*256 + t;
    int o = (i / 5120) & 7;
    float val = s[o];
    ((float4*)out)[i] = make_float4(val, val, val, val);
}

extern "C" void kernel_launch(void* const* d_in, const int* in_sizes, int n_in,
                              void* d_out, int out_size, void* d_ws, size_t ws_size,
                              hipStream_t stream)
{
    const float* up16 = (const float*)d_in[0];
    const float* up8  = (const float*)d_in[1];
    const float* up4  = (const float*)d_in[2];
    const float* HM[6]; const float* DEP[6]; const float* DIM[6]; const float* ROT[6];
    for (int i = 0; i < 6; ++i) {
        HM[i]  = (const float*)d_in[3+i];
        DEP[i] = (const float*)d_in[9+i];
        DIM[i] = (const float*)d_in[15+i];
        ROT[i] = (const float*)d_in[21+i];
    }
    const float* hm_w2 = (const float*)d_in[27];
    const float* hm_b2 = (const float*)d_in[28];
    const float* r3_w  = (const float*)d_in[29];
    const float* r3_b  = (const float*)d_in[30];

    float* out = (float*)d_out;
    float* heat   = out;
    float* dep    = heat + 368640LL;
    float* scores = dep + 3*31457280LL;
    float* pois   = scores + 400;
    float* reg3   = pois + 153600;

    float* s1s = (float*)d_ws;
    int*   s1i = (int*)(s1s + 1200);
    int*   sel = s1i + 1200;

    size_t need = 16384 + 2*15728640ull + 1474560ull;
    if (ws_size >= need) {
        ushort* Xhi = (ushort*)((char*)d_ws + 16384);
        ushort* Xlo = Xhi + 7864320;
        ushort* Wt  = Xlo + 7864320;
        prep_x<<<dim3(3840), dim3(256), 0, stream>>>(up4, Xhi, Xlo);
        prep_w<<<dim3(2880), dim3(256), 0, stream>>>(DEP[0], DIM[0], ROT[0], HM[0], Wt);
        HeadP hd = {DEP[1], DEP[2], DEP[3], DEP[4], DEP[5]};
        HeadP hi_ = {DIM[1], DIM[2], DIM[3], DIM[4], DIM[5]};
        HeadP hr = {ROT[1], ROT[2], ROT[3], ROT[4], ROT[5]};
        HeadP hh = {HM[1], HM[2], HM[3], HM[4], HM[5]};
        conv3_mfma<<<dim3(1920,3), dim3(256), 0, stream>>>(Xhi, Wt, hd, hi_, hr, dep);
        convhm_mfma<<<dim3(1920), dim3(256), 0, stream>>>(Xhi, Xlo, Wt, hh, hm_w2, hm_b2, heat);
    } else {
        dim3 blk(256), grd(1920);
        conv_head<<<grd, blk, 0, stream>>>(up4, DEP[0], DEP[1], DEP[2], DEP[3], DEP[4], DEP[5],
                                           dep, nullptr, nullptr, nullptr, 0);
        conv_head<<<grd, blk, 0, stream>>>(up4, DIM[0], DIM[1], DIM[2], DIM[3], DIM[4], DIM[5],
                                           dep + 31457280LL, nullptr, nullptr, nullptr, 0);
        conv_head<<<grd, blk, 0, stream>>>(up4, ROT[0], ROT[1], ROT[2], ROT[3], ROT[4], ROT[5],
                                           dep + 2*31457280LL, nullptr, nullptr, nullptr, 0);
        conv_head<<<grd, blk, 0, stream>>>(up4, HM[0], HM[1], HM[2], HM[3], HM[4], HM[5],
                                           nullptr, hm_w2, hm_b2, heat, 1);
    }
    topk_stage1<<<dim3(12), dim3(256), 0, stream>>>(heat, s1s, s1i);
    topk_stage2<<<dim3(4), dim3(64), 0, stream>>>(s1s, s1i, scores, sel);
    gather_pois<<<dim3(400), dim3(384), 0, stream>>>(up8, up16, sel, pois);
    reg3d_fill<<<dim3(1280), dim3(256), 0, stream>>>(r3_w, r3_b, reg3);
}